// Round 18
// baseline (73.227 us; speedup 1.0000x reference)
//
#include <hip/hip_runtime.h>
#include <math.h>

#define BB 4
#define DIM 192
#define HEADS 8
#define HD 24

typedef __attribute__((ext_vector_type(8))) short short8v;
typedef __attribute__((ext_vector_type(4))) short short4v;
typedef __attribute__((ext_vector_type(4))) float f32x4;
typedef __attribute__((ext_vector_type(4))) unsigned uint4v;

__device__ __forceinline__ short f2bf(float f) {
  unsigned u = __builtin_bit_cast(unsigned, f);
  u += 0x7FFF + ((u >> 16) & 1);
  return (short)(u >> 16);
}
// hardware packed fp32x2 -> bf16x2 (RNE, same results as f2bf pair)
__device__ __forceinline__ unsigned pk2(float a, float b) {
  unsigned r;
  asm("v_cvt_pk_bf16_f32 %0, %1, %2" : "=v"(r) : "v"(a), "v"(b));
  return r;
}
__device__ __forceinline__ float bf2f(unsigned u16) {
  return __builtin_bit_cast(float, u16 << 16);
}
__device__ __forceinline__ void gl_lds16(const void* g, void* l) {
  __builtin_amdgcn_global_load_lds(
      (const __attribute__((address_space(1))) unsigned int*)g,
      (__attribute__((address_space(3))) unsigned int*)l, 16, 0, 0);
}
// bijective XCD swizzle (m204): contiguous chunks per XCD
__device__ __forceinline__ int xcd_swz(int bid, int nwg) {
  int q = nwg >> 3, r = nwg & 7;
  int xcd = bid & 7, idx = bid >> 3;
  return (xcd < r) ? (xcd * (q + 1) + idx) : (r * (q + 1) + (xcd - r) * q + idx);
}

// ================= prep: weight cvt, input transpose, bfin =================
struct PJob {
  int type;  // 0 cvt fp32->bf16; 1 transpose-cvt [B][C][X]->[B*X][C]; 2 bfin
  const float* s0; const float* s1; const float* s2;
  void* dst;
  int P0, P1v;
  int t_begin, t_end;
};
struct PJobs { PJob j[20]; };

__global__ __launch_bounds__(256) void prep_k(PJobs jobs, int nj) {
  int tid = blockIdx.x * 256 + threadIdx.x;
  for (int ji = 0; ji < 20; ++ji) {
    if (ji >= nj) return;
    PJob g = jobs.j[ji];
    if (tid < g.t_begin || tid >= g.t_end) continue;
    int t = tid - g.t_begin;
    if (g.type == 0) {
      float4 v = *(const float4*)&g.s0[(size_t)t * 4];
      uint2 u = {pk2(v.x, v.y), pk2(v.z, v.w)};
      *(uint2*)&((short*)g.dst)[(size_t)t * 4] = u;
    } else if (g.type == 1) {
      int X = g.P0, C = g.P1v, C8 = C >> 3;
      int x = t % X, c8 = (t / X) % C8, b = t / (X * C8);
      const float* s = g.s0 + ((size_t)b * C + c8 * 8) * X + x;
      float v[8];
#pragma unroll
      for (int j = 0; j < 8; ++j) v[j] = s[(size_t)j * X];
      uint4 u = {pk2(v[0], v[1]), pk2(v[2], v[3]), pk2(v[4], v[5]), pk2(v[6], v[7])};
      *(uint4*)&((short*)g.dst)[((size_t)b * X + x) * C + c8 * 8] = u;
    } else {
      int o = t;
      const float* w = g.s0 + (size_t)o * 192;
      float acc = g.s2[o];
      for (int k = 0; k < 192; ++k) acc += w[k] * g.s1[k];
      ((float*)g.dst)[o] = acc;
    }
    return;
  }
}

// ================= tiled MFMA GEMM: C = A * W^T =================
// mode 0: bf16 row-major out, swapped operands, *scale + bias
// mode 1: bf16 chan-major out, 32-group permuted (V)
// mode 2: fp32 chan-major + T residual
// mode 3: fp32 chan-major + bias[o]
// mode 4: dual-source: acc = A*W^T + A2*W2p^T; fp32 chan-major + bias[o]
struct MJob {
  const short* A; const short* W; const float* bias; const float* T;
  void* out;
  int K, nOT, mode, tokPerB;
  float scale;
  int blk_begin, blk_end;
  const short* A2; const short* W2p;  // trailing: value-init nullptr when omitted
};
struct MJobs { MJob j[10]; };

__global__ __launch_bounds__(256) void mgemm_k(MJobs jobs, int nj, int nwg) {
  __shared__ short Asl[64 * 192];
  __shared__ short Wsl[64 * 192];
  int blk = xcd_swz(blockIdx.x, nwg);
  for (int ji = 0; ji < 10; ++ji) {
    if (ji >= nj) return;
    MJob g = jobs.j[ji];
    if (blk < g.blk_begin || blk >= g.blk_end) continue;
    int lb = blk - g.blk_begin;
    int ot = lb % g.nOT, tt = lb / g.nOT;
    int t0 = tt * 64, o0 = ot * 64;
    int tid = threadIdx.x, wv = tid >> 6, lane = tid & 63, c = lane & 15, qi = lane >> 4;
    const int K = g.K;
    int rowK[6];
#pragma unroll
    for (int i = 0; i < 6; ++i) {
      int o16 = i * 256 + tid;
      int row = o16 / 24, ch = o16 - row * 24;
      rowK[i] = row * K + ((ch ^ (row & 7)) << 3);
    }
    const short* Ab = g.A + (size_t)t0 * K;
    const short* Wb = g.W + (size_t)o0 * K;
    f32x4 acc[4];
#pragma unroll
    for (int jj = 0; jj < 4; ++jj) acc[jj] = (f32x4){0.f, 0.f, 0.f, 0.f};
    int nkc = (g.mode == 4) ? 2 : K / 192;
    int swz = c & 7;
    for (int kc = 0; kc < nkc; ++kc) {
      if (kc) __syncthreads();
      const short* Asrc;
      const short* Wsrc;
      int kco;
      if (g.mode == 4 && kc) {
        Asrc = g.A2 + (size_t)t0 * 192;
        Wsrc = g.W2p + (size_t)o0 * 192;
        kco = 0;
      } else {
        Asrc = Ab;
        Wsrc = Wb;
        kco = kc * 192;
      }
#pragma unroll
      for (int i = 0; i < 6; ++i) gl_lds16(Asrc + rowK[i] + kco, &Asl[(i * 256 + wv * 64) * 8]);
#pragma unroll
      for (int i = 0; i < 6; ++i) gl_lds16(Wsrc + rowK[i] + kco, &Wsl[(i * 256 + wv * 64) * 8]);
      asm volatile("s_waitcnt vmcnt(0)" ::: "memory");
      __syncthreads();
      const short* Lb = (g.mode == 0) ? Wsl : Asl;
      const short* Rb = (g.mode == 0) ? Asl : Wsl;
      int lrow = wv * 16 + c;
#pragma unroll
      for (int ks = 0; ks < 6; ++ks) {
        int chx = ((ks * 4 + qi) ^ swz) << 3;
        short8v lf = *(const short8v*)&Lb[lrow * 192 + chx];
#pragma unroll
        for (int jj = 0; jj < 4; ++jj) {
          short8v rf = *(const short8v*)&Rb[(jj * 16 + c) * 192 + chx];
          acc[jj] = __builtin_amdgcn_mfma_f32_16x16x32_bf16(lf, rf, acc[jj], 0, 0, 0);
        }
      }
    }
    int OST = g.nOT * 64;
    if (g.mode == 0) {
      int ob = o0 + wv * 16 + (qi << 2);
      float4 bv = {0.f, 0.f, 0.f, 0.f};
      if (g.bias) bv = *(const float4*)&g.bias[ob];
      float s = g.scale;
      short* op = (short*)g.out;
#pragma unroll
      for (int jj = 0; jj < 4; ++jj) {
        size_t tok = t0 + jj * 16 + c;
        uint2 u = {pk2(acc[jj][0] * s + bv.x, acc[jj][1] * s + bv.y),
                   pk2(acc[jj][2] * s + bv.z, acc[jj][3] * s + bv.w)};
        *(uint2*)&op[tok * OST + ob] = u;
      }
    } else {
      int tokb = t0 + wv * 16;
      int b = tokb / g.tokPerB;
      int nl = tokb - b * g.tokPerB + (qi << 2);
#pragma unroll
      for (int jj = 0; jj < 4; ++jj) {
        int o = o0 + jj * 16 + c;
        if (g.mode == 1) {
          // permuted within 32-token groups: slot(m=16h+4q+r) = 8q+4h+r
          // -> attn PV reads one b128 per (row,ks)
          int np = (nl & ~31) + 8 * ((nl >> 2) & 3) + 4 * ((nl >> 4) & 1);
          size_t idx = ((size_t)b * OST + o) * g.tokPerB + np;
          uint2 u = {pk2(acc[jj][0], acc[jj][1]), pk2(acc[jj][2], acc[jj][3])};
          *(uint2*)&((short*)g.out)[idx] = u;
        } else if (g.mode == 2) {
          size_t idx = ((size_t)b * OST + o) * g.tokPerB + nl;
          float4 tv = *(const float4*)&g.T[idx];
          float4 ov = {acc[jj][0] + tv.x, acc[jj][1] + tv.y, acc[jj][2] + tv.z, acc[jj][3] + tv.w};
          *(float4*)&((float*)g.out)[idx] = ov;
        } else {
          size_t idx = ((size_t)b * OST + o) * g.tokPerB + nl;
          float bvv = g.bias ? g.bias[o] : 0.f;
          float4 ov = {acc[jj][0] + bvv, acc[jj][1] + bvv, acc[jj][2] + bvv, acc[jj][3] + bvv};
          *(float4*)&((float*)g.out)[idx] = ov;
        }
      }
    }
    return;
  }
}

// ================= bilinear resize, bf16 token rows =================
struct RJob {
  const short* src;
  short* dst;
  int Hs, Ws, Wd, Mtot;
  float ry, rx;
  int t_begin, t_end;
};
struct RJobs { RJob j[6]; };

__global__ __launch_bounds__(256) void resize_k(RJobs jobs) {
  int tid = blockIdx.x * 256 + threadIdx.x;
  for (int ji = 0; ji < 6; ++ji) {
    RJob g = jobs.j[ji];
    if (tid < g.t_begin || tid >= g.t_end) continue;
    int t = tid - g.t_begin;
    int c8 = t % 24;
    int rest = t / 24;
    int HWd = g.Wd * g.Wd;
    int n = rest % HWd, b = rest / HWd;
    int y = n / g.Wd, x = n % g.Wd;
    float fy = (y + 0.5f) * g.ry - 0.5f;
    float fx = (x + 0.5f) * g.rx - 0.5f;
    int y0 = (int)floorf(fy), x0 = (int)floorf(fx);
    float wy = fy - (float)y0, wx = fx - (float)x0;
    int Hs = g.Hs, Ws = g.Ws;
    int y0c = min(max(y0, 0), Hs - 1), y1c = min(max(y0 + 1, 0), Hs - 1);
    int x0c = min(max(x0, 0), Ws - 1), x1c = min(max(x0 + 1, 0), Ws - 1);
    size_t sb = (size_t)b * Hs * Ws;
    const short* sp = g.src;
    uint4 u00 = *(const uint4*)&sp[(sb + y0c * Ws + x0c) * 192 + c8 * 8];
    uint4 u01 = *(const uint4*)&sp[(sb + y0c * Ws + x1c) * 192 + c8 * 8];
    uint4 u10 = *(const uint4*)&sp[(sb + y1c * Ws + x0c) * 192 + c8 * 8];
    uint4 u11 = *(const uint4*)&sp[(sb + y1c * Ws + x1c) * 192 + c8 * 8];
    float w00 = (1.f - wy) * (1.f - wx), w01 = (1.f - wy) * wx;
    float w10 = wy * (1.f - wx), w11 = wy * wx;
    unsigned a[4], bq[4], cq[4], dq[4];
    a[0]=u00.x; a[1]=u00.y; a[2]=u00.z; a[3]=u00.w;
    bq[0]=u01.x; bq[1]=u01.y; bq[2]=u01.z; bq[3]=u01.w;
    cq[0]=u10.x; cq[1]=u10.y; cq[2]=u10.z; cq[3]=u10.w;
    dq[0]=u11.x; dq[1]=u11.y; dq[2]=u11.z; dq[3]=u11.w;
    unsigned r[4];
#pragma unroll
    for (int k = 0; k < 4; ++k) {
      float lo = w00 * bf2f(a[k] & 0xffff) + w01 * bf2f(bq[k] & 0xffff) +
                 w10 * bf2f(cq[k] & 0xffff) + w11 * bf2f(dq[k] & 0xffff);
      float hi = w00 * bf2f(a[k] >> 16) + w01 * bf2f(bq[k] >> 16) +
                 w10 * bf2f(cq[k] >> 16) + w11 * bf2f(dq[k] >> 16);
      r[k] = pk2(lo, hi);
    }
    uint4 u = {r[0], r[1], r[2], r[3]};
    *(uint4*)&g.dst[((size_t)b * g.Mtot + n) * 192 + c8 * 8] = u;
    return;
  }
}

// ==== MFMA flash attention: 2-buf counted-vmcnt pipeline, 4 blocks/CU ====
// 64 q rows/block (16/wave), KVBLK=128. q pre-scaled by 24^-0.5*log2e -> P=exp2(S).
// Per buffer (7432 shorts): K [0,3072) 128x24 (+8 zero guard);
// V [3080,7432) stride 136, rows 0..23 staged, row 24 = bf16 ones (lsum via PV).
struct AJob {
  const short* q;   // [B*N][192] bf16 pre-scaled (incl. log2e)
  const short* K;   // [B*M][192] bf16
  const short* V;   // [B][192][M] bf16 chan-major, 32-group permuted
  short* o;         // [B*N][192] bf16
  int N, M;
  int blk_begin, blk_end;
};
struct AJobs { AJob j[3]; };

#define ABUF 7432
#define VBASE 3080

__global__ __launch_bounds__(256, 4) void attn_k(AJobs jobs, int cpx) {
  __shared__ __align__(16) short LDSbuf[2][ABUF];
  int bid = blockIdx.x;
  int blk = (bid & 7) * cpx + (bid >> 3);
  int tidx = threadIdx.x;
  // init once: K zero guard; V row 24 = 1.0 bf16 (never staged over)
  if (tidx < 64) {
#pragma unroll
    for (int bb = 0; bb < 2; ++bb)
      ((int*)&LDSbuf[bb][VBASE + 24 * 136])[tidx] = 0x3F803F80;
  } else if (tidx < 72) {
    int bb = (tidx - 64) >> 2, e = (tidx - 64) & 3;
    ((int*)&LDSbuf[bb][3072])[e] = 0;
  }
  for (int ji = 0; ji < 3; ++ji) {
    AJob g = jobs.j[ji];
    if (blk < g.blk_begin || blk >= g.blk_end) continue;
    int lb = blk - g.blk_begin;
    const int N = g.N, M = g.M;
    int nch = N >> 6;
    int bh = lb / nch, ct = lb % nch;
    int b = bh >> 3, h = bh & 7;
    int wv = tidx >> 6, lane = tidx & 63;
    int c = lane & 15, qi = lane >> 4;
    int nw0 = (ct << 6) + (wv << 4);  // this wave's 16 q rows

    const short* Kg = g.K + (size_t)b * M * 192 + h * 24;
    const short* Vg = g.V + ((size_t)b * 192 + h * 24) * M;

    // staging descriptors: 792 16B slots (K 384 + V 408), <=4 per thread
    const short* gp[4];
    int gstr[4], loff[4];
    bool val[4];
#pragma unroll
    for (int i = 0; i < 4; ++i) {
      int s = tidx + (i << 8);
      val[i] = (s < 792);
      if (s < 384) {
        int row = s / 3, part = s - row * 3;
        gp[i] = Kg + row * 192 + part * 8;
        gstr[i] = 128 * 192;
        loff[i] = s * 8;
      } else {
        int v = s - 384;
        int row = v / 17, col = v - row * 17;
        int colc = (col < 16) ? col : 0;
        gp[i] = val[i] ? (Vg + (size_t)row * M + colc * 8) : Vg;
        gstr[i] = 128;
        loff[i] = VBASE + v * 8;
      }
    }

    // Q fragment (pre-scaled incl. log2e); qi==3 zeroed (k-pad 24..31)
    short8v qf = *(const short8v*)&g.q[((size_t)b * N + nw0 + c) * 192 + h * 24 + (qi << 3)];
    if (qi == 3) {
#pragma unroll
      for (int j = 0; j < 8; ++j) qf[j] = 0;
    }

    f32x4 of0 = {0.f, 0.f, 0.f, 0.f}, of1 = {0.f, 0.f, 0.f, 0.f};
    const f32x4 zf = {0.f, 0.f, 0.f, 0.f};

    int nt = M >> 7;
    // prologue: stage tile 0 -> buf0, tile 1 -> buf1
#pragma unroll
    for (int i = 0; i < 4; ++i)
      if (val[i]) { gl_lds16(gp[i], &LDSbuf[0][loff[i]]); gp[i] += gstr[i]; }
    if (nt > 1) {
#pragma unroll
      for (int i = 0; i < 4; ++i)
        if (val[i]) { gl_lds16(gp[i], &LDSbuf[1][loff[i]]); gp[i] += gstr[i]; }
    }

    for (int t = 0; t < nt; ++t) {
      // counted wait: tile t complete; tile t+1 loads may stay in flight
      if (t + 1 < nt) asm volatile("s_waitcnt vmcnt(3) lgkmcnt(0)" ::: "memory");
      else            asm volatile("s_waitcnt vmcnt(0) lgkmcnt(0)" ::: "memory");
      __builtin_amdgcn_s_barrier();
      const short* Kl = LDSbuf[t & 1];
      const short* Vl = Kl + VBASE;
      // swapped QK^T: sr[jj][r] = S[n=c][m=16jj+4qi+r] (lane-local P)
      __builtin_amdgcn_s_setprio(1);
      f32x4 sr[8];
#pragma unroll
      for (int jj = 0; jj < 8; ++jj) {
        short8v kb = *(const short8v*)&Kl[(c + 16 * jj) * 24 + (qi << 3)];
        sr[jj] = __builtin_amdgcn_mfma_f32_16x16x32_bf16(kb, qf, zf, 0, 0, 0);
      }
      __builtin_amdgcn_s_setprio(0);
      // P = exp2(S') (one v_exp_f32 each) + hw cvt_pk pack, all lane-local
      unsigned pk[8][2];
#pragma unroll
      for (int jj = 0; jj < 8; ++jj) {
        float e0 = __builtin_amdgcn_exp2f(sr[jj][0]);
        float e1 = __builtin_amdgcn_exp2f(sr[jj][1]);
        float e2 = __builtin_amdgcn_exp2f(sr[jj][2]);
        float e3 = __builtin_amdgcn_exp2f(sr[jj][3]);
        pk[jj][0] = pk2(e0, e1);
        pk[jj][1] = pk2(e2, e3);
      }
      // PV: V pre-permuted in memory -> one b128 per (row, ks)
      __builtin_amdgcn_s_setprio(1);
#pragma unroll
      for (int ks = 0; ks < 4; ++ks) {
        uint4v pu = {pk[2 * ks][0], pk[2 * ks][1], pk[2 * ks + 1][0], pk[2 * ks + 1][1]};
        short8v pa = __builtin_bit_cast(short8v, pu);
        short8v v0 = *(const short8v*)&Vl[c * 136 + ks * 32 + (qi << 3)];
        short8v v1 = *(const short8v*)&Vl[(16 + c) * 136 + ks * 32 + (qi << 3)];
        of0 = __builtin_amdgcn_mfma_f32_16x16x32_bf16(pa, v0, of0, 0, 0, 0);
        of1 = __builtin_amdgcn_mfma_f32_16x16x32_bf16(pa, v1, of1, 0, 0, 0);
      }
      __builtin_amdgcn_s_setprio(0);
      // all waves done reading buf[t&1]; restage it with tile t+2
      __builtin_amdgcn_sched_barrier(0);
      __builtin_amdgcn_s_barrier();
      __builtin_amdgcn_sched_barrier(0);
      if (t + 2 < nt) {
        short* dst = LDSbuf[t & 1];
#pragma unroll
        for (int i = 0; i < 4; ++i)
          if (val[i]) { gl_lds16(gp[i], &dst[loff[i]]); gp[i] += gstr[i]; }
      }
    }
    // lsum[n] = O[n][d=24] (ones-row) lives in of1[r] at lanes c==8
    float ls[4];
#pragma unroll
    for (int r = 0; r < 4; ++r) ls[r] = __shfl(of1[r], (qi << 4) + 8);
#pragma unroll
    for (int r = 0; r < 4; ++r) {
      float inv = 1.f / ls[r];
      int n = nw0 + (qi << 2) + r;
      short* op = g.o + ((size_t)b * N + n) * 192 + h * 24;
      op[c] = f2bf(of0[r] * inv);
      if (c < 8) op[16 + c] = f2bf(of1[r] * inv);
    }
    return;
  }
}

// ================= host =================
extern "C" void kernel_launch(void* const* d_in, const int* in_sizes, int n_in,
                              void* d_out, int out_size, void* d_ws, size_t ws_size,
                              hipStream_t stream) {
  (void)in_sizes; (void)n_in; (void)out_size; (void)ws_size;
  const float* f0 = (const float*)d_in[0];
  const float* f1 = (const float*)d_in[1];
  const float* f2 = (const float*)d_in[2];
  const float* p1w = (const float*)d_in[3];
  const float* p1b = (const float*)d_in[4];
  const float* p2w = (const float*)d_in[5];
  const float* p2b = (const float*)d_in[6];
  const float* qw[3]  = {(const float*)d_in[7],  (const float*)d_in[11], (const float*)d_in[15]};
  const float* kvw[3] = {(const float*)d_in[8],  (const float*)d_in[12], (const float*)d_in[16]};
  const float* prw[3] = {(const float*)d_in[9],  (const float*)d_in[13], (const float*)d_in[17]};
  const float* prb[3] = {(const float*)d_in[10], (const float*)d_in[14], (const float*)d_in[18]};
  const float* ow[3]  = {(const float*)d_in[19], (const float*)d_in[21], (const float*)d_in[23]};
  const float* ob[3]  = {(const float*)d_in[20], (const float*)d_in[22], (const float*)d_in[24]};

  char* ws = (char*)d_ws;
  short* x0    = (short*)(ws + 0);         // [4096][192]
  short* x1in  = (short*)(ws + 1572864);   // [1024][384]
  short* x2in  = (short*)(ws + 2359296);   // [256][768]
  short* P1    = (short*)(ws + 2752512);   // [1024][192]
  short* P2    = (short*)(ws + 3145728);   // [256][192]
  short* ctx0  = (short*)(ws + 3244032);   // [8192][192]
  short* ctx1  = (short*)(ws + 6389760);   // [2048][192]
  short* ctx2  = (short*)(ws + 7176192);   // [512][192]
  short* qb    = (short*)(ws + 7372800);   // [5376][192]
  short* Kb    = (short*)(ws + 9437184);   // [10752][192]
  short* Vb    = (short*)(ws + 13565952);  // [10752][192] chan-major per scale
  short* attb  = (short*)(ws + 17694720);  // [5376][192]
  short* W2b   = (short*)(ws + 25264128);  // [1344][192]
  short* wcvt  = (short*)(ws + 25780224);
  float* bfin  = (float*)(ws + 27402240);  // [1344]
  short* prwT  = (short*)(ws + 27407616);  // 3 x [192][192] transposed proj weights

  short* p1w_b = wcvt;
  short* p2w_b = wcvt + 73728;
  short* qw_b[3]  = {wcvt + 221184, wcvt + 258048, wcvt + 294912};
  short* kvw_b[3] = {wcvt + 331776, wcvt + 405504, wcvt + 479232};
  short* ow_b[3]  = {wcvt + 552960, wcvt + 589824, wcvt + 663552};
  short* prwT_b[3] = {prwT, prwT + 36864, prwT + 73728};
  short* W2_b[3]  = {W2b, W2b + 36864, W2b + 110592};
  short* qs[3]  = {qb, qb + 786432, qb + 983040};
  short* Ks[3]  = {Kb, Kb + 1572864, Kb + 1966080};
  short* Vs[3]  = {Vb, Vb + 1572864, Vb + 1966080};
  short* atts[3] = {attb, attb + 786432, attb + 983040};
  const short* feat[3] = {x0, P1, P2};
  float* out0 = (float*)d_out;
  float* outp[3] = {out0, out0 + 786432, out0 + 1179648};

  const int Ns[3] = {1024, 256, 64};
  const int Ms[3] = {2048, 512, 128};
  const int Couts[3] = {192, 384, 768};
  // 24^-0.5 * log2(e): P computed as exp2(S') with one v_exp_f32
  const float qsc = 0.2944888902728332f;

  // ---- L0: prep (cvts, transposes incl. prw^T, bfin) ----
  {
    PJobs js{};
    int t0 = 0, n = 0;
    auto add = [&](PJob j, int tc) { j.t_begin = t0; j.t_end = t0 + tc; js.j[n++] = j; t0 += tc; };
    add({0, p1w, nullptr, nullptr, p1w_b, 0, 0, 0, 0}, 18432);
    add({0, p2w, nullptr, nullptr, p2w_b, 0, 0, 0, 0}, 36864);
    for (int i = 0; i < 3; ++i) add({0, qw[i], nullptr, nullptr, qw_b[i], 0, 0, 0, 0}, 9216);
    for (int i = 0; i < 3; ++i) add({0, kvw[i], nullptr, nullptr, kvw_b[i], 0, 0, 0, 0}, 18432);
    add({0, ow[0], nullptr, nullptr, ow_b[0], 0, 0, 0, 0}, 9216);
    add({0, ow[1], nullptr, nullptr, ow_b[1], 0, 0, 0, 0}, 18432);
    add({0, ow[2], nullptr, nullptr, ow_b[2], 0, 0, 0, 0}, 36864);
    add({1, f0, nullptr, nullptr, x0, 1024, 192, 0, 0}, 98304);
    add({1, f1, nullptr, nullptr, x1in, 256, 384, 0, 0}, 49152);
    add({1, f2, nullptr, nullptr, x2in, 64, 768, 0, 0}, 24576);
    for (int i = 0; i < 3; ++i)
      add({1, prw[i], nullptr, nullptr, prwT_b[i], 192, 192, 0, 0}, 4608);
    add({2, ow[0], prb[0], ob[0], bfin, 0, 0, 0, 0}, 192);
    add({2, ow[1], prb[1], ob[1], bfin + 192, 0, 0, 0, 0}, 384);
    add({2, ow[2], prb[2], ob[2], bfin + 576, 0, 0, 0, 0}, 768);
    hipLaunchKernelGGL(prep_k, dim3((t0 + 255) / 256), dim3(256), 0, stream, js, n);
  }
  // ---- L1: P1, P2, q0, W2_i = OW_i * prw_i ----
  {
    MJobs js{};
    int b0 = 0, n = 0;
    auto add = [&](MJob j, int nb) { j.blk_begin = b0; j.blk_end = b0 + nb; js.j[n++] = j; b0 += nb; };
    add({x1in, p1w_b, p1b, nullptr, P1, 384, 3, 0, 0, 1.f, 0, 0}, 16 * 3);
    add({x2in, p2w_b, p2b, nullptr, P2, 768, 3, 0, 0, 1.f, 0, 0}, 4 * 3);
    add({x0, qw_b[0], nullptr, nullptr, qs[0], 192, 3, 0, 0, qsc, 0, 0}, 64 * 3);
    for (int i = 0; i < 3; ++i)
      add({ow_b[i], prwT_b[i], nullptr, nullptr, W2_b[i], 192, 3, 0, 0, 1.f, 0, 0},
          (Couts[i] / 64) * 3);
    hipLaunchKernelGGL(mgemm_k, dim3(b0), dim3(256), 0, stream, js, n, b0);
  }
  // ---- L2: resizes -> ctx (bf16) ----
  {
    RJobs js{};
    int t0 = 0, n = 0;
    auto add = [&](RJob j, int tc) { j.t_begin = t0; j.t_end = t0 + tc; js.j[n++] = j; t0 += tc; };
    add({P1, ctx0, 16, 16, 32, 2048, 0.5f, 0.5f, 0, 0}, 98304);
    add({P2, ctx0 + 1024 * 192, 8, 8, 32, 2048, 0.25f, 0.25f, 0, 0}, 98304);
    add({x0, ctx1, 32, 32, 16, 512, 2.f, 2.f, 0, 0}, 24576);
    add({P2, ctx1 + 256 * 192, 8, 8, 16, 512, 0.5f, 0.5f, 0, 0}, 24576);
    add({x0, ctx2, 32, 32, 8, 128, 4.f, 4.f, 0, 0}, 6144);
    add({P1, ctx2 + 64 * 192, 16, 16, 8, 128, 2.f, 2.f, 0, 0}, 6144);
    hipLaunchKernelGGL(resize_k, dim3(t0 / 256), dim3(256), 0, stream, js);
  }
  // ---- L3: q1, q2, K_i, V_i (V permuted store) ----
  {
    MJobs js{};
    int b0 = 0, n = 0;
    auto add = [&](MJob j, int nb) { j.blk_begin = b0; j.blk_end = b0 + nb; js.j[n++] = j; b0 += nb; };
    add({P1, qw_b[1], nullptr, nullptr, qs[1], 192, 3, 0, 0, qsc, 0, 0}, 16 * 3);
    add({P2, qw_b[2], nullptr, nullptr, qs[2], 192, 3, 0, 0, qsc, 0, 0}, 4 * 3);
    add({ctx0, kvw_b[0], nullptr, nullptr, Ks[0], 192, 3, 0, 0, 1.f, 0, 0}, 128 * 3);
    add({ctx1, kvw_b[1], nullptr, nullptr, Ks[1], 192, 3, 0, 0, 1.f, 0, 0}, 32 * 3);
    add({ctx2, kvw_b[2], nullptr, nullptr, Ks[2], 192, 3, 0, 0, 1.f, 0, 0}, 8 * 3);
    add({ctx0, kvw_b[0] + 36864, nullptr, nullptr, Vs[0], 192, 3, 1, 2048, 1.f, 0, 0}, 128 * 3);
    add({ctx1, kvw_b[1] + 36864, nullptr, nullptr, Vs[1], 192, 3, 1, 512, 1.f, 0, 0}, 32 * 3);
    add({ctx2, kvw_b[2] + 36864, nullptr, nullptr, Vs[2], 192, 3, 1, 128, 1.f, 0, 0}, 8 * 3);
    hipLaunchKernelGGL(mgemm_k, dim3(b0), dim3(256), 0, stream, js, n, b0);
  }
  // ---- L4: attention (64-row blocks; grid 672 = 8*84) ----
  {
    AJobs js{};
    int b0 = 0;
    for (int i = 0; i < 3; ++i) {
      int nb = BB * HEADS * (Ns[i] / 64);
      js.j[i] = {qs[i], Ks[i], Vs[i], atts[i], Ns[i], Ms[i], b0, b0 + nb};
      b0 += nb;
    }
    hipLaunchKernelGGL(attn_k, dim3(b0), dim3(256), 0, stream, js, b0 / 8);
  }
  // ---- L5: out = att*W2^T + feat*OW^T + bfin -> d_out (mode 4 dual GEMM) ----
  {
    MJobs js{};
    int b0 = 0, n = 0;
    auto add = [&](MJob j, int nb) { j.blk_begin = b0; j.blk_end = b0 + nb; js.j[n++] = j; b0 += nb; };
    const float* bslice[3] = {bfin, bfin + 192, bfin + 576};
    for (int i = 0; i < 3; ++i) {
      MJob j = {atts[i], W2_b[i], bslice[i], nullptr, outp[i],
                192, Couts[i] / 64, 4, Ns[i], 1.f, 0, 0, feat[i], ow_b[i]};
      add(j, (Ns[i] * 4 / 64) * (Couts[i] / 64));
    }
    hipLaunchKernelGGL(mgemm_k, dim3(b0), dim3(256), 0, stream, js, n, b0);
  }
}

// Round 19
// 72.283 us; speedup vs baseline: 1.0130x; 1.0130x over previous
//
#include <hip/hip_runtime.h>
#include <math.h>

#define BB 4
#define DIM 192
#define HEADS 8
#define HD 24

typedef __attribute__((ext_vector_type(8))) short short8v;
typedef __attribute__((ext_vector_type(4))) short short4v;
typedef __attribute__((ext_vector_type(4))) float f32x4;
typedef __attribute__((ext_vector_type(4))) unsigned uint4v;

__device__ __forceinline__ short f2bf(float f) {
  unsigned u = __builtin_bit_cast(unsigned, f);
  u += 0x7FFF + ((u >> 16) & 1);
  return (short)(u >> 16);
}
// hardware packed fp32x2 -> bf16x2 (RNE, same results as f2bf pair)
__device__ __forceinline__ unsigned pk2(float a, float b) {
  unsigned r;
  asm("v_cvt_pk_bf16_f32 %0, %1, %2" : "=v"(r) : "v"(a), "v"(b));
  return r;
}
__device__ __forceinline__ float bf2f(unsigned u16) {
  return __builtin_bit_cast(float, u16 << 16);
}
__device__ __forceinline__ void gl_lds16(const void* g, void* l) {
  __builtin_amdgcn_global_load_lds(
      (const __attribute__((address_space(1))) unsigned int*)g,
      (__attribute__((address_space(3))) unsigned int*)l, 16, 0, 0);
}
// bijective XCD swizzle (m204): contiguous chunks per XCD
__device__ __forceinline__ int xcd_swz(int bid, int nwg) {
  int q = nwg >> 3, r = nwg & 7;
  int xcd = bid & 7, idx = bid >> 3;
  return (xcd < r) ? (xcd * (q + 1) + idx) : (r * (q + 1) + (xcd - r) * q + idx);
}

// ================= prep: weight cvt, input transpose, bfin =================
struct PJob {
  int type;  // 0 cvt fp32->bf16; 1 transpose-cvt [B][C][X]->[B*X][C]; 2 bfin
  const float* s0; const float* s1; const float* s2;
  void* dst;
  int P0, P1v;
  int t_begin, t_end;
};
struct PJobs { PJob j[20]; };

__global__ __launch_bounds__(256) void prep_k(PJobs jobs, int nj) {
  int tid = blockIdx.x * 256 + threadIdx.x;
  for (int ji = 0; ji < 20; ++ji) {
    if (ji >= nj) return;
    PJob g = jobs.j[ji];
    if (tid < g.t_begin || tid >= g.t_end) continue;
    int t = tid - g.t_begin;
    if (g.type == 0) {
      float4 v = *(const float4*)&g.s0[(size_t)t * 4];
      uint2 u = {pk2(v.x, v.y), pk2(v.z, v.w)};
      *(uint2*)&((short*)g.dst)[(size_t)t * 4] = u;
    } else if (g.type == 1) {
      int X = g.P0, C = g.P1v, C8 = C >> 3;
      int x = t % X, c8 = (t / X) % C8, b = t / (X * C8);
      const float* s = g.s0 + ((size_t)b * C + c8 * 8) * X + x;
      float v[8];
#pragma unroll
      for (int j = 0; j < 8; ++j) v[j] = s[(size_t)j * X];
      uint4 u = {pk2(v[0], v[1]), pk2(v[2], v[3]), pk2(v[4], v[5]), pk2(v[6], v[7])};
      *(uint4*)&((short*)g.dst)[((size_t)b * X + x) * C + c8 * 8] = u;
    } else {
      int o = t;
      const float* w = g.s0 + (size_t)o * 192;
      float acc = g.s2[o];
      for (int k = 0; k < 192; ++k) acc += w[k] * g.s1[k];
      ((float*)g.dst)[o] = acc;
    }
    return;
  }
}

// ================= tiled MFMA GEMM: C = A * W^T =================
// mode 0: bf16 row-major out, swapped operands, *scale + bias
// mode 1: bf16 chan-major out, 32-group permuted (V)
// mode 2: fp32 chan-major + T residual
// mode 3: fp32 chan-major + bias[o]
// mode 4: dual-source: acc = A*W^T + A2*W2p^T; fp32 chan-major + bias[o]
struct MJob {
  const short* A; const short* W; const float* bias; const float* T;
  void* out;
  int K, nOT, mode, tokPerB;
  float scale;
  int blk_begin, blk_end;
  const short* A2; const short* W2p;  // trailing: value-init nullptr when omitted
};
struct MJobs { MJob j[10]; };

__global__ __launch_bounds__(256) void mgemm_k(MJobs jobs, int nj, int nwg) {
  __shared__ short Asl[64 * 192];
  __shared__ short Wsl[64 * 192];
  int blk = xcd_swz(blockIdx.x, nwg);
  for (int ji = 0; ji < 10; ++ji) {
    if (ji >= nj) return;
    MJob g = jobs.j[ji];
    if (blk < g.blk_begin || blk >= g.blk_end) continue;
    int lb = blk - g.blk_begin;
    int ot = lb % g.nOT, tt = lb / g.nOT;
    int t0 = tt * 64, o0 = ot * 64;
    int tid = threadIdx.x, wv = tid >> 6, lane = tid & 63, c = lane & 15, qi = lane >> 4;
    const int K = g.K;
    int rowK[6];
#pragma unroll
    for (int i = 0; i < 6; ++i) {
      int o16 = i * 256 + tid;
      int row = o16 / 24, ch = o16 - row * 24;
      rowK[i] = row * K + ((ch ^ (row & 7)) << 3);
    }
    const short* Ab = g.A + (size_t)t0 * K;
    const short* Wb = g.W + (size_t)o0 * K;
    f32x4 acc[4];
#pragma unroll
    for (int jj = 0; jj < 4; ++jj) acc[jj] = (f32x4){0.f, 0.f, 0.f, 0.f};
    int nkc = (g.mode == 4) ? 2 : K / 192;
    int swz = c & 7;
    for (int kc = 0; kc < nkc; ++kc) {
      if (kc) __syncthreads();
      const short* Asrc;
      const short* Wsrc;
      int kco;
      if (g.mode == 4 && kc) {
        Asrc = g.A2 + (size_t)t0 * 192;
        Wsrc = g.W2p + (size_t)o0 * 192;
        kco = 0;
      } else {
        Asrc = Ab;
        Wsrc = Wb;
        kco = kc * 192;
      }
#pragma unroll
      for (int i = 0; i < 6; ++i) gl_lds16(Asrc + rowK[i] + kco, &Asl[(i * 256 + wv * 64) * 8]);
#pragma unroll
      for (int i = 0; i < 6; ++i) gl_lds16(Wsrc + rowK[i] + kco, &Wsl[(i * 256 + wv * 64) * 8]);
      asm volatile("s_waitcnt vmcnt(0)" ::: "memory");
      __syncthreads();
      const short* Lb = (g.mode == 0) ? Wsl : Asl;
      const short* Rb = (g.mode == 0) ? Asl : Wsl;
      int lrow = wv * 16 + c;
#pragma unroll
      for (int ks = 0; ks < 6; ++ks) {
        int chx = ((ks * 4 + qi) ^ swz) << 3;
        short8v lf = *(const short8v*)&Lb[lrow * 192 + chx];
#pragma unroll
        for (int jj = 0; jj < 4; ++jj) {
          short8v rf = *(const short8v*)&Rb[(jj * 16 + c) * 192 + chx];
          acc[jj] = __builtin_amdgcn_mfma_f32_16x16x32_bf16(lf, rf, acc[jj], 0, 0, 0);
        }
      }
    }
    int OST = g.nOT * 64;
    if (g.mode == 0) {
      int ob = o0 + wv * 16 + (qi << 2);
      float4 bv = {0.f, 0.f, 0.f, 0.f};
      if (g.bias) bv = *(const float4*)&g.bias[ob];
      float s = g.scale;
      short* op = (short*)g.out;
#pragma unroll
      for (int jj = 0; jj < 4; ++jj) {
        size_t tok = t0 + jj * 16 + c;
        uint2 u = {pk2(acc[jj][0] * s + bv.x, acc[jj][1] * s + bv.y),
                   pk2(acc[jj][2] * s + bv.z, acc[jj][3] * s + bv.w)};
        *(uint2*)&op[tok * OST + ob] = u;
      }
    } else {
      int tokb = t0 + wv * 16;
      int b = tokb / g.tokPerB;
      int nl = tokb - b * g.tokPerB + (qi << 2);
#pragma unroll
      for (int jj = 0; jj < 4; ++jj) {
        int o = o0 + jj * 16 + c;
        if (g.mode == 1) {
          // permuted within 32-token groups: slot(m=16h+4q+r) = 8q+4h+r
          // -> attn PV reads one b128 per (row,ks)
          int np = (nl & ~31) + 8 * ((nl >> 2) & 3) + 4 * ((nl >> 4) & 1);
          size_t idx = ((size_t)b * OST + o) * g.tokPerB + np;
          uint2 u = {pk2(acc[jj][0], acc[jj][1]), pk2(acc[jj][2], acc[jj][3])};
          *(uint2*)&((short*)g.out)[idx] = u;
        } else if (g.mode == 2) {
          size_t idx = ((size_t)b * OST + o) * g.tokPerB + nl;
          float4 tv = *(const float4*)&g.T[idx];
          float4 ov = {acc[jj][0] + tv.x, acc[jj][1] + tv.y, acc[jj][2] + tv.z, acc[jj][3] + tv.w};
          *(float4*)&((float*)g.out)[idx] = ov;
        } else {
          size_t idx = ((size_t)b * OST + o) * g.tokPerB + nl;
          float bvv = g.bias ? g.bias[o] : 0.f;
          float4 ov = {acc[jj][0] + bvv, acc[jj][1] + bvv, acc[jj][2] + bvv, acc[jj][3] + bvv};
          *(float4*)&((float*)g.out)[idx] = ov;
        }
      }
    }
    return;
  }
}

// ================= bilinear resize, bf16 token rows =================
struct RJob {
  const short* src;
  short* dst;
  int Hs, Ws, Wd, Mtot;
  float ry, rx;
  int t_begin, t_end;
};
struct RJobs { RJob j[6]; };

__global__ __launch_bounds__(256) void resize_k(RJobs jobs) {
  int tid = blockIdx.x * 256 + threadIdx.x;
  for (int ji = 0; ji < 6; ++ji) {
    RJob g = jobs.j[ji];
    if (tid < g.t_begin || tid >= g.t_end) continue;
    int t = tid - g.t_begin;
    int c8 = t % 24;
    int rest = t / 24;
    int HWd = g.Wd * g.Wd;
    int n = rest % HWd, b = rest / HWd;
    int y = n / g.Wd, x = n % g.Wd;
    float fy = (y + 0.5f) * g.ry - 0.5f;
    float fx = (x + 0.5f) * g.rx - 0.5f;
    int y0 = (int)floorf(fy), x0 = (int)floorf(fx);
    float wy = fy - (float)y0, wx = fx - (float)x0;
    int Hs = g.Hs, Ws = g.Ws;
    int y0c = min(max(y0, 0), Hs - 1), y1c = min(max(y0 + 1, 0), Hs - 1);
    int x0c = min(max(x0, 0), Ws - 1), x1c = min(max(x0 + 1, 0), Ws - 1);
    size_t sb = (size_t)b * Hs * Ws;
    const short* sp = g.src;
    uint4 u00 = *(const uint4*)&sp[(sb + y0c * Ws + x0c) * 192 + c8 * 8];
    uint4 u01 = *(const uint4*)&sp[(sb + y0c * Ws + x1c) * 192 + c8 * 8];
    uint4 u10 = *(const uint4*)&sp[(sb + y1c * Ws + x0c) * 192 + c8 * 8];
    uint4 u11 = *(const uint4*)&sp[(sb + y1c * Ws + x1c) * 192 + c8 * 8];
    float w00 = (1.f - wy) * (1.f - wx), w01 = (1.f - wy) * wx;
    float w10 = wy * (1.f - wx), w11 = wy * wx;
    unsigned a[4], bq[4], cq[4], dq[4];
    a[0]=u00.x; a[1]=u00.y; a[2]=u00.z; a[3]=u00.w;
    bq[0]=u01.x; bq[1]=u01.y; bq[2]=u01.z; bq[3]=u01.w;
    cq[0]=u10.x; cq[1]=u10.y; cq[2]=u10.z; cq[3]=u10.w;
    dq[0]=u11.x; dq[1]=u11.y; dq[2]=u11.z; dq[3]=u11.w;
    unsigned r[4];
#pragma unroll
    for (int k = 0; k < 4; ++k) {
      float lo = w00 * bf2f(a[k] & 0xffff) + w01 * bf2f(bq[k] & 0xffff) +
                 w10 * bf2f(cq[k] & 0xffff) + w11 * bf2f(dq[k] & 0xffff);
      float hi = w00 * bf2f(a[k] >> 16) + w01 * bf2f(bq[k] >> 16) +
                 w10 * bf2f(cq[k] >> 16) + w11 * bf2f(dq[k] >> 16);
      r[k] = pk2(lo, hi);
    }
    uint4 u = {r[0], r[1], r[2], r[3]};
    *(uint4*)&g.dst[((size_t)b * g.Mtot + n) * 192 + c8 * 8] = u;
    return;
  }
}

// ==== MFMA flash attention: 3-buf counted-vmcnt pipeline, wave-pair m-split ====
struct AJob {
  const short* q;   // [B*N][192] bf16 pre-scaled (incl. log2e)
  const short* K;   // [B*M][192] bf16
  const short* V;   // [B][192][M] bf16 chan-major, 32-group permuted
  short* o;         // [B*N][192] bf16
  int N, M;
  int blk_begin, blk_end;
};
struct AJobs { AJob j[3]; };

#define ABUF 7432
#define VBASE 3080

__global__ __launch_bounds__(256, 3) void attn_k(AJobs jobs, int cpx) {
  __shared__ __align__(16) short LDSbuf[3][ABUF];
  __shared__ __align__(16) float scr[2048];  // 8KB combine scratch
  int bid = blockIdx.x;
  int blk = (bid & 7) * cpx + (bid >> 3);
  int tidx = threadIdx.x;
  // init once: K zero guard; V row 24 = 1.0 bf16 (never staged over)
  if (tidx < 64) {
#pragma unroll
    for (int bb = 0; bb < 3; ++bb)
      ((int*)&LDSbuf[bb][VBASE + 24 * 136])[tidx] = 0x3F803F80;
  } else if (tidx < 76) {
    int bb = (tidx - 64) >> 2, e = (tidx - 64) & 3;
    ((int*)&LDSbuf[bb][3072])[e] = 0;
  }
  for (int ji = 0; ji < 3; ++ji) {
    AJob g = jobs.j[ji];
    if (blk < g.blk_begin || blk >= g.blk_end) continue;
    int lb = blk - g.blk_begin;
    const int N = g.N, M = g.M;
    int nch = N >> 6;
    int bh = lb / nch, ct = lb % nch;
    int b = bh >> 3, h = bh & 7;
    int wv = tidx >> 6, lane = tidx & 63;
    int c = lane & 15, qi = lane >> 4;
    int w1 = wv & 1, mh = wv >> 1;
    int qbase = (ct << 6) + (w1 << 5);  // this wave's 32 q rows

    const short* Kg = g.K + (size_t)b * M * 192 + h * 24;
    const short* Vg = g.V + ((size_t)b * 192 + h * 24) * M;

    // staging descriptors: 792 16B slots (K 384 + V 408), <=4 per thread
    const short* gp[4];
    int gstr[4], loff[4];
    bool val[4];
#pragma unroll
    for (int i = 0; i < 4; ++i) {
      int s = tidx + (i << 8);
      val[i] = (s < 792);
      if (s < 384) {
        int row = s / 3, part = s - row * 3;
        gp[i] = Kg + row * 192 + part * 8;
        gstr[i] = 128 * 192;
        loff[i] = s * 8;
      } else {
        int v = s - 384;
        int row = v / 17, col = v - row * 17;
        int colc = (col < 16) ? col : 0;
        gp[i] = val[i] ? (Vg + (size_t)row * M + colc * 8) : Vg;
        gstr[i] = 128;
        loff[i] = VBASE + v * 8;
      }
    }

    // two Q fragments: rows qbase+c and qbase+16+c; qi==3 zeroed (k-pad 24..31)
    short8v qf1 = *(const short8v*)&g.q[((size_t)b * N + qbase + c) * 192 + h * 24 + (qi << 3)];
    short8v qf2 = *(const short8v*)&g.q[((size_t)b * N + qbase + 16 + c) * 192 + h * 24 + (qi << 3)];
    if (qi == 3) {
#pragma unroll
      for (int j = 0; j < 8; ++j) { qf1[j] = 0; qf2[j] = 0; }
    }

    f32x4 of0 = {0.f, 0.f, 0.f, 0.f}, of1 = {0.f, 0.f, 0.f, 0.f};
    f32x4 of2 = {0.f, 0.f, 0.f, 0.f}, of3 = {0.f, 0.f, 0.f, 0.f};
    const f32x4 zf = {0.f, 0.f, 0.f, 0.f};

    int nt = M >> 7;
    // prologue: stage tiles 0 (buf0) and 1 (buf1)
#pragma unroll
    for (int i = 0; i < 4; ++i)
      if (val[i]) { gl_lds16(gp[i], &LDSbuf[0][loff[i]]); gp[i] += gstr[i]; }
    if (nt > 1) {
#pragma unroll
      for (int i = 0; i < 4; ++i)
        if (val[i]) { gl_lds16(gp[i], &LDSbuf[1][loff[i]]); gp[i] += gstr[i]; }
    }

    for (int t = 0; t < nt; ++t) {
      if (t + 1 < nt) asm volatile("s_waitcnt vmcnt(3) lgkmcnt(0)" ::: "memory");
      else            asm volatile("s_waitcnt vmcnt(0) lgkmcnt(0)" ::: "memory");
      __builtin_amdgcn_s_barrier();
      if (t + 2 < nt) {
        short* dst = LDSbuf[(t + 2) % 3];
#pragma unroll
        for (int i = 0; i < 4; ++i)
          if (val[i]) { gl_lds16(gp[i], &dst[loff[i]]); gp[i] += gstr[i]; }
      }
      const short* Kl = LDSbuf[t % 3];
      const short* Vl = Kl + VBASE;
      // swapped QK^T on this wave's m-half: each kb read feeds BOTH Q frags
      __builtin_amdgcn_s_setprio(1);
      f32x4 s1[4], s2[4];
#pragma unroll
      for (int jj = 0; jj < 4; ++jj) {
        short8v kb = *(const short8v*)&Kl[((mh << 6) + c + 16 * jj) * 24 + (qi << 3)];
        s1[jj] = __builtin_amdgcn_mfma_f32_16x16x32_bf16(kb, qf1, zf, 0, 0, 0);
        s2[jj] = __builtin_amdgcn_mfma_f32_16x16x32_bf16(kb, qf2, zf, 0, 0, 0);
      }
      __builtin_amdgcn_s_setprio(0);
      // P = exp2(S') + hw cvt_pk pack, all lane-local
      unsigned pk1[4][2], pk2a[4][2];
#pragma unroll
      for (int jj = 0; jj < 4; ++jj) {
        pk1[jj][0] = pk2(__builtin_amdgcn_exp2f(s1[jj][0]), __builtin_amdgcn_exp2f(s1[jj][1]));
        pk1[jj][1] = pk2(__builtin_amdgcn_exp2f(s1[jj][2]), __builtin_amdgcn_exp2f(s1[jj][3]));
        pk2a[jj][0] = pk2(__builtin_amdgcn_exp2f(s2[jj][0]), __builtin_amdgcn_exp2f(s2[jj][1]));
        pk2a[jj][1] = pk2(__builtin_amdgcn_exp2f(s2[jj][2]), __builtin_amdgcn_exp2f(s2[jj][3]));
      }
      // PV: each V read feeds BOTH P frags (V pre-permuted -> one b128 each)
      __builtin_amdgcn_s_setprio(1);
#pragma unroll
      for (int ks = 0; ks < 2; ++ks) {
        uint4v pu1 = {pk1[2 * ks][0], pk1[2 * ks][1], pk1[2 * ks + 1][0], pk1[2 * ks + 1][1]};
        uint4v pu2 = {pk2a[2 * ks][0], pk2a[2 * ks][1], pk2a[2 * ks + 1][0], pk2a[2 * ks + 1][1]};
        short8v pa1 = __builtin_bit_cast(short8v, pu1);
        short8v pa2 = __builtin_bit_cast(short8v, pu2);
        int gcol = ((mh << 1) + ks) * 32 + (qi << 3);
        short8v v0 = *(const short8v*)&Vl[c * 136 + gcol];
        short8v v1 = *(const short8v*)&Vl[(16 + c) * 136 + gcol];
        of0 = __builtin_amdgcn_mfma_f32_16x16x32_bf16(pa1, v0, of0, 0, 0, 0);
        of1 = __builtin_amdgcn_mfma_f32_16x16x32_bf16(pa1, v1, of1, 0, 0, 0);
        of2 = __builtin_amdgcn_mfma_f32_16x16x32_bf16(pa2, v0, of2, 0, 0, 0);
        of3 = __builtin_amdgcn_mfma_f32_16x16x32_bf16(pa2, v1, of3, 0, 0, 0);
      }
      __builtin_amdgcn_s_setprio(0);
    }
    // combine m-halves: mh=1 waves park partials in scratch, mh=0 waves reduce
    if (mh) {
      float* sp = &scr[w1 * 1024];
      *(f32x4*)&sp[0 * 256 + lane * 4] = of0;
      *(f32x4*)&sp[1 * 256 + lane * 4] = of1;
      *(f32x4*)&sp[2 * 256 + lane * 4] = of2;
      *(f32x4*)&sp[3 * 256 + lane * 4] = of3;
    }
    asm volatile("s_waitcnt lgkmcnt(0)" ::: "memory");
    __builtin_amdgcn_sched_barrier(0);
    __builtin_amdgcn_s_barrier();
    if (!mh) {
      const float* sp = &scr[w1 * 1024];
      of0 += *(const f32x4*)&sp[0 * 256 + lane * 4];
      of1 += *(const f32x4*)&sp[1 * 256 + lane * 4];
      of2 += *(const f32x4*)&sp[2 * 256 + lane * 4];
      of3 += *(const f32x4*)&sp[3 * 256 + lane * 4];
      // lsum[n] = O[n][d=24] (ones-row) at lanes c==8 of the d-hi accums
      float ls1[4], ls2[4];
#pragma unroll
      for (int r = 0; r < 4; ++r) {
        ls1[r] = __shfl(of1[r], (qi << 4) + 8);
        ls2[r] = __shfl(of3[r], (qi << 4) + 8);
      }
#pragma unroll
      for (int r = 0; r < 4; ++r) {
        float inv1 = 1.f / ls1[r];
        int n1 = qbase + (qi << 2) + r;
        short* op1 = g.o + ((size_t)b * N + n1) * 192 + h * 24;
        op1[c] = f2bf(of0[r] * inv1);
        if (c < 8) op1[16 + c] = f2bf(of1[r] * inv1);
        float inv2 = 1.f / ls2[r];
        int n2 = qbase + 16 + (qi << 2) + r;
        short* op2 = g.o + ((size_t)b * N + n2) * 192 + h * 24;
        op2[c] = f2bf(of2[r] * inv2);
        if (c < 8) op2[16 + c] = f2bf(of3[r] * inv2);
      }
    }
    return;
  }
}

// ================= host =================
extern "C" void kernel_launch(void* const* d_in, const int* in_sizes, int n_in,
                              void* d_out, int out_size, void* d_ws, size_t ws_size,
                              hipStream_t stream) {
  (void)in_sizes; (void)n_in; (void)out_size; (void)ws_size;
  const float* f0 = (const float*)d_in[0];
  const float* f1 = (const float*)d_in[1];
  const float* f2 = (const float*)d_in[2];
  const float* p1w = (const float*)d_in[3];
  const float* p1b = (const float*)d_in[4];
  const float* p2w = (const float*)d_in[5];
  const float* p2b = (const float*)d_in[6];
  const float* qw[3]  = {(const float*)d_in[7],  (const float*)d_in[11], (const float*)d_in[15]};
  const float* kvw[3] = {(const float*)d_in[8],  (const float*)d_in[12], (const float*)d_in[16]};
  const float* prw[3] = {(const float*)d_in[9],  (const float*)d_in[13], (const float*)d_in[17]};
  const float* prb[3] = {(const float*)d_in[10], (const float*)d_in[14], (const float*)d_in[18]};
  const float* ow[3]  = {(const float*)d_in[19], (const float*)d_in[21], (const float*)d_in[23]};
  const float* ob[3]  = {(const float*)d_in[20], (const float*)d_in[22], (const float*)d_in[24]};

  char* ws = (char*)d_ws;
  short* x0    = (short*)(ws + 0);         // [4096][192]
  short* x1in  = (short*)(ws + 1572864);   // [1024][384]
  short* x2in  = (short*)(ws + 2359296);   // [256][768]
  short* P1    = (short*)(ws + 2752512);   // [1024][192]
  short* P2    = (short*)(ws + 3145728);   // [256][192]
  short* ctx0  = (short*)(ws + 3244032);   // [8192][192]
  short* ctx1  = (short*)(ws + 6389760);   // [2048][192]
  short* ctx2  = (short*)(ws + 7176192);   // [512][192]
  short* qb    = (short*)(ws + 7372800);   // [5376][192]
  short* Kb    = (short*)(ws + 9437184);   // [10752][192]
  short* Vb    = (short*)(ws + 13565952);  // [10752][192] chan-major per scale
  short* attb  = (short*)(ws + 17694720);  // [5376][192]
  short* W2b   = (short*)(ws + 25264128);  // [1344][192]
  short* wcvt  = (short*)(ws + 25780224);
  float* bfin  = (float*)(ws + 27402240);  // [1344]
  short* prwT  = (short*)(ws + 27407616);  // 3 x [192][192] transposed proj weights

  short* p1w_b = wcvt;
  short* p2w_b = wcvt + 73728;
  short* qw_b[3]  = {wcvt + 221184, wcvt + 258048, wcvt + 294912};
  short* kvw_b[3] = {wcvt + 331776, wcvt + 405504, wcvt + 479232};
  short* ow_b[3]  = {wcvt + 552960, wcvt + 589824, wcvt + 663552};
  short* prwT_b[3] = {prwT, prwT + 36864, prwT + 73728};
  short* W2_b[3]  = {W2b, W2b + 36864, W2b + 110592};
  short* qs[3]  = {qb, qb + 786432, qb + 983040};
  short* Ks[3]  = {Kb, Kb + 1572864, Kb + 1966080};
  short* Vs[3]  = {Vb, Vb + 1572864, Vb + 1966080};
  short* atts[3] = {attb, attb + 786432, attb + 983040};
  const short* feat[3] = {x0, P1, P2};
  float* out0 = (float*)d_out;
  float* outp[3] = {out0, out0 + 786432, out0 + 1179648};

  const int Ns[3] = {1024, 256, 64};
  const int Ms[3] = {2048, 512, 128};
  const int Couts[3] = {192, 384, 768};
  // 24^-0.5 * log2(e): P computed as exp2(S') with one v_exp_f32
  const float qsc = 0.2944888902728332f;

  // ---- L0: prep (cvts, transposes incl. prw^T, bfin) ----
  {
    PJobs js{};
    int t0 = 0, n = 0;
    auto add = [&](PJob j, int tc) { j.t_begin = t0; j.t_end = t0 + tc; js.j[n++] = j; t0 += tc; };
    add({0, p1w, nullptr, nullptr, p1w_b, 0, 0, 0, 0}, 18432);
    add({0, p2w, nullptr, nullptr, p2w_b, 0, 0, 0, 0}, 36864);
    for (int i = 0; i < 3; ++i) add({0, qw[i], nullptr, nullptr, qw_b[i], 0, 0, 0, 0}, 9216);
    for (int i = 0; i < 3; ++i) add({0, kvw[i], nullptr, nullptr, kvw_b[i], 0, 0, 0, 0}, 18432);
    add({0, ow[0], nullptr, nullptr, ow_b[0], 0, 0, 0, 0}, 9216);
    add({0, ow[1], nullptr, nullptr, ow_b[1], 0, 0, 0, 0}, 18432);
    add({0, ow[2], nullptr, nullptr, ow_b[2], 0, 0, 0, 0}, 36864);
    add({1, f0, nullptr, nullptr, x0, 1024, 192, 0, 0}, 98304);
    add({1, f1, nullptr, nullptr, x1in, 256, 384, 0, 0}, 49152);
    add({1, f2, nullptr, nullptr, x2in, 64, 768, 0, 0}, 24576);
    for (int i = 0; i < 3; ++i)
      add({1, prw[i], nullptr, nullptr, prwT_b[i], 192, 192, 0, 0}, 4608);
    add({2, ow[0], prb[0], ob[0], bfin, 0, 0, 0, 0}, 192);
    add({2, ow[1], prb[1], ob[1], bfin + 192, 0, 0, 0, 0}, 384);
    add({2, ow[2], prb[2], ob[2], bfin + 576, 0, 0, 0, 0}, 768);
    hipLaunchKernelGGL(prep_k, dim3((t0 + 255) / 256), dim3(256), 0, stream, js, n);
  }
  // ---- L1: P1, P2, W2_i = OW_i * prw_i (MFMA fold) ----
  {
    MJobs js{};
    int b0 = 0, n = 0;
    auto add = [&](MJob j, int nb) { j.blk_begin = b0; j.blk_end = b0 + nb; js.j[n++] = j; b0 += nb; };
    add({x1in, p1w_b, p1b, nullptr, P1, 384, 3, 0, 0, 1.f, 0, 0}, 16 * 3);
    add({x2in, p2w_b, p2b, nullptr, P2, 768, 3, 0, 0, 1.f, 0, 0}, 4 * 3);
    for (int i = 0; i < 3; ++i)
      add({ow_b[i], prwT_b[i], nullptr, nullptr, W2_b[i], 192, 3, 0, 0, 1.f, 0, 0},
          (Couts[i] / 64) * 3);
    hipLaunchKernelGGL(mgemm_k, dim3(b0), dim3(256), 0, stream, js, n, b0);
  }
  // ---- L2: resizes -> ctx (bf16) ----
  {
    RJobs js{};
    int t0 = 0, n = 0;
    auto add = [&](RJob j, int tc) { j.t_begin = t0; j.t_end = t0 + tc; js.j[n++] = j; t0 += tc; };
    add({P1, ctx0, 16, 16, 32, 2048, 0.5f, 0.5f, 0, 0}, 98304);
    add({P2, ctx0 + 1024 * 192, 8, 8, 32, 2048, 0.25f, 0.25f, 0, 0}, 98304);
    add({x0, ctx1, 32, 32, 16, 512, 2.f, 2.f, 0, 0}, 24576);
    add({P2, ctx1 + 256 * 192, 8, 8, 16, 512, 0.5f, 0.5f, 0, 0}, 24576);
    add({x0, ctx2, 32, 32, 8, 128, 4.f, 4.f, 0, 0}, 6144);
    add({P1, ctx2 + 64 * 192, 16, 16, 8, 128, 2.f, 2.f, 0, 0}, 6144);
    hipLaunchKernelGGL(resize_k, dim3(t0 / 256), dim3(256), 0, stream, js);
  }
  // ---- L3: q0, q1, q2, K_i, V_i (V permuted store) ----
  {
    MJobs js{};
    int b0 = 0, n = 0;
    auto add = [&](MJob j, int nb) { j.blk_begin = b0; j.blk_end = b0 + nb; js.j[n++] = j; b0 += nb; };
    add({x0, qw_b[0], nullptr, nullptr, qs[0], 192, 3, 0, 0, qsc, 0, 0}, 64 * 3);
    add({P1, qw_b[1], nullptr, nullptr, qs[1], 192, 3, 0, 0, qsc, 0, 0}, 16 * 3);
    add({P2, qw_b[2], nullptr, nullptr, qs[2], 192, 3, 0, 0, qsc, 0, 0}, 4 * 3);
    add({ctx0, kvw_b[0], nullptr, nullptr, Ks[0], 192, 3, 0, 0, 1.f, 0, 0}, 128 * 3);
    add({ctx1, kvw_b[1], nullptr, nullptr, Ks[1], 192, 3, 0, 0, 1.f, 0, 0}, 32 * 3);
    add({ctx2, kvw_b[2], nullptr, nullptr, Ks[2], 192, 3, 0, 0, 1.f, 0, 0}, 8 * 3);
    add({ctx0, kvw_b[0] + 36864, nullptr, nullptr, Vs[0], 192, 3, 1, 2048, 1.f, 0, 0}, 128 * 3);
    add({ctx1, kvw_b[1] + 36864, nullptr, nullptr, Vs[1], 192, 3, 1, 512, 1.f, 0, 0}, 32 * 3);
    add({ctx2, kvw_b[2] + 36864, nullptr, nullptr, Vs[2], 192, 3, 1, 128, 1.f, 0, 0}, 8 * 3);
    hipLaunchKernelGGL(mgemm_k, dim3(b0), dim3(256), 0, stream, js, n, b0);
  }
  // ---- L4: attention (64-row blocks; grid 672 = 8*84) ----
  {
    AJobs js{};
    int b0 = 0;
    for (int i = 0; i < 3; ++i) {
      int nb = BB * HEADS * (Ns[i] / 64);
      js.j[i] = {qs[i], Ks[i], Vs[i], atts[i], Ns[i], Ms[i], b0, b0 + nb};
      b0 += nb;
    }
    hipLaunchKernelGGL(attn_k, dim3(b0), dim3(256), 0, stream, js, b0 / 8);
  }
  // ---- L5: out = att*W2^T + feat*OW^T + bfin -> d_out (mode 4 dual GEMM) ----
  {
    MJobs js{};
    int b0 = 0, n = 0;
    auto add = [&](MJob j, int nb) { j.blk_begin = b0; j.blk_end = b0 + nb; js.j[n++] = j; b0 += nb; };
    const float* bslice[3] = {bfin, bfin + 192, bfin + 576};
    for (int i = 0; i < 3; ++i) {
      MJob j = {atts[i], W2_b[i], bslice[i], nullptr, outp[i],
                192, Couts[i] / 64, 4, Ns[i], 1.f, 0, 0, feat[i], ow_b[i]};
      add(j, (Ns[i] * 4 / 64) * (Couts[i] / 64));
    }
    hipLaunchKernelGGL(mgemm_k, dim3(b0), dim3(256), 0, stream, js, n, b0);
  }
}